// Round 4
// baseline (445.903 us; speedup 1.0000x reference)
//
#include <hip/hip_runtime.h>
#include <math.h>

#define S_N 8
#define U_N 8
#define K_N 6
#define NNEG 17
#define ZDIM 64
#define CDIM 256
#define LEN 512
#define TDIM (LEN + K_N)   // 518

typedef __attribute__((ext_vector_type(8))) short short8;
typedef __attribute__((ext_vector_type(4))) short short4v;
typedef __attribute__((ext_vector_type(4))) float f32x4;

__device__ __forceinline__ short f2bf(float x) {
    unsigned u = __builtin_bit_cast(unsigned, x);
    return (short)((u + 0x7fffu + ((u >> 16) & 1u)) >> 16);   // RNE
}

// Fused CPC loss kernel, MFMA phase 1.
// grid = K*S*U*8 = 3072 blocks, 256 threads (4 waves).
// Block: lt8 = bid&7 (l-tile of 64), su = (bid>>3)&63, k = bid>>9.
// Phase 1: Wc[ll][z] = sum_c c[su][l0+ll][c] * W[k][z][c] + b[k][z]
//   - W[k] staged once to LDS as bf16, 16B-chunk XOR swizzle (chb ^ (row&7))
//   - A-fragments straight from global (no intra-block A reuse), cvt to bf16
//   - wave w owns m-tile w (16 l-rows), all 4 n-tiles, 8 k-chunks -> 32 MFMA
// Phase 2: 18 logits per l (1 pos + 17 gathered negs), logsumexp + argmax,
//   block-reduce, atomicAdd.  (unchanged from verified baseline)

__global__ __launch_bounds__(256, 3) void cpc_fused(
    const float* __restrict__ zg, const float* __restrict__ cg_,
    const float* __restrict__ Wg, const float* __restrict__ bg,
    const int* __restrict__ bidx, const int* __restrict__ sidx,
    float* __restrict__ out)
{
    __shared__ __align__(16) short wlds[ZDIM * CDIM];  // bf16 W[k], swizzled
    __shared__ float wc[64][68];                        // [ll][z], +4 pad
    __shared__ float red[8];

    const int tid = threadIdx.x;
    const int bid = blockIdx.x;
    const int lt8 = bid & 7;
    const int su  = (bid >> 3) & 63;
    const int k   = bid >> 9;
    const int s   = su >> 3;
    const int u   = su & 7;
    const int l0  = lt8 * 64;

    const int wave   = tid >> 6;
    const int lane   = tid & 63;
    const int lane15 = lane & 15;
    const int lgrp   = lane >> 4;

    // ---------------- stage W[k] -> LDS bf16, swizzled ----------------
    {
        const float* wbase = Wg + (size_t)k * ZDIM * CDIM;
        #pragma unroll
        for (int it = 0; it < 16; ++it) {
            int off = it * 1024 + tid * 4;        // f32 index into 64x256
            int r = off >> 8;                      // z row
            int c = off & 255;                     // c col
            float4 v = *(const float4*)(wbase + off);
            short4v h;
            h.x = f2bf(v.x); h.y = f2bf(v.y); h.z = f2bf(v.z); h.w = f2bf(v.w);
            int chb = c >> 3;                      // 16B chunk within row
            int hh  = (c >> 2) & 1;
            *(short4v*)&wlds[r * 256 + ((chb ^ (r & 7)) << 3) + hh * 4] = h;
        }
    }
    __syncthreads();

    // ---------------- Phase 1: MFMA GEMM ----------------
    {
        const int lrow = l0 + wave * 16 + lane15;  // global l for A-frag
        const float* arow = cg_ + ((size_t)(su * TDIM + lrow)) * CDIM;
        f32x4 acc[4] = {{0.f,0.f,0.f,0.f},{0.f,0.f,0.f,0.f},
                        {0.f,0.f,0.f,0.f},{0.f,0.f,0.f,0.f}};
        for (int kc = 0; kc < 8; ++kc) {
            const float* ap = arow + kc * 32 + lgrp * 8;
            float4 a0 = *(const float4*)(ap);
            float4 a1 = *(const float4*)(ap + 4);
            short8 af;
            af[0]=f2bf(a0.x); af[1]=f2bf(a0.y); af[2]=f2bf(a0.z); af[3]=f2bf(a0.w);
            af[4]=f2bf(a1.x); af[5]=f2bf(a1.y); af[6]=f2bf(a1.z); af[7]=f2bf(a1.w);
            #pragma unroll
            for (int n = 0; n < 4; ++n) {
                int z = n * 16 + lane15;
                short8 bf_ = *(const short8*)&wlds[z * 256 + (((kc * 4 + lgrp) ^ (z & 7)) << 3)];
                acc[n] = __builtin_amdgcn_mfma_f32_16x16x32_bf16(af, bf_, acc[n], 0, 0, 0);
            }
        }
        // bias + write Wc tile to LDS.  D: col = lane&15, row = lgrp*4 + reg
        #pragma unroll
        for (int n = 0; n < 4; ++n) {
            float bias = bg[k * ZDIM + n * 16 + lane15];
            #pragma unroll
            for (int r = 0; r < 4; ++r) {
                wc[wave * 16 + lgrp * 4 + r][n * 16 + lane15] = acc[n][r] + bias;
            }
        }
    }
    __syncthreads();

    // ---------------- Phase 2: logits, logsumexp, reduce ----------------
    const int lt = tid >> 2;   // l within tile
    const int jq = tid & 3;    // 4 lanes split the 18 logits: j = jq + 4*t
    const int l  = l0 + lt;

    float fv[5];
    #pragma unroll
    for (int t = 0; t < 5; ++t) {
        int j = jq + 4 * t;
        if (j >= 18) { fv[t] = -1e30f; continue; }
        const float* zp;
        if (j == 0) {
            zp = zg + ((size_t)(su * TDIM + (k + 1 + l))) * ZDIM;
        } else {
            int n  = j - 1;
            int bi = bidx[(k * U_N + u) * NNEG + n];
            int si = sidx[(size_t)((((k * S_N + s) * U_N + u) * NNEG + n)) * LEN + l];
            zp = zg + ((size_t)((s * U_N + bi) * TDIM + (k + 1 + si))) * ZDIM;
        }
        float f = 0.f;
        const float* wr = &wc[lt][0];
        #pragma unroll
        for (int c4 = 0; c4 < 16; ++c4) {
            float4 zv = *(const float4*)(zp + c4 * 4);
            float4 wv = *(const float4*)(wr + c4 * 4);
            f = fmaf(zv.x, wv.x, f);
            f = fmaf(zv.y, wv.y, f);
            f = fmaf(zv.z, wv.z, f);
            f = fmaf(zv.w, wv.w, f);
        }
        fv[t] = f * 0.125f;
    }

    float mall = -1e30f, mneg = -1e30f;
    #pragma unroll
    for (int t = 0; t < 5; ++t) {
        mall = fmaxf(mall, fv[t]);
        bool skip = (jq == 0 && t == 0) || (jq + 4 * t >= 18);
        if (!skip) mneg = fmaxf(mneg, fv[t]);
    }
    mall = fmaxf(mall, __shfl_xor(mall, 1));
    mall = fmaxf(mall, __shfl_xor(mall, 2));
    mneg = fmaxf(mneg, __shfl_xor(mneg, 1));
    mneg = fmaxf(mneg, __shfl_xor(mneg, 2));

    float se = 0.f;
    #pragma unroll
    for (int t = 0; t < 5; ++t) {
        if (jq + 4 * t < 18) se += __expf(fv[t] - mall);
    }
    se += __shfl_xor(se, 1);
    se += __shfl_xor(se, 2);

    float lossv = 0.f, accv = 0.f;
    if (jq == 0) {
        lossv = (mall + __logf(se)) - fv[0];
        accv  = (fv[0] >= mneg) ? 1.f : 0.f;
    }

    // block reduce (wave shuffle + LDS across 4 waves)
    #pragma unroll
    for (int off = 1; off < 64; off <<= 1) {
        lossv += __shfl_xor(lossv, off);
        accv  += __shfl_xor(accv, off);
    }
    const int wv = tid >> 6;
    if ((tid & 63) == 0) { red[wv * 2] = lossv; red[wv * 2 + 1] = accv; }
    __syncthreads();
    if (tid == 0) {
        float ls = red[0] + red[2] + red[4] + red[6];
        float ac = red[1] + red[3] + red[5] + red[7];
        atomicAdd(out, ls * (1.0f / 196608.0f));          // mean over K*S*U*L
        atomicAdd(out + 1 + k, ac * (1.0f / 32768.0f));   // mean over S*U*L
    }
}

extern "C" void kernel_launch(void* const* d_in, const int* in_sizes, int n_in,
                              void* d_out, int out_size, void* d_ws, size_t ws_size,
                              hipStream_t stream) {
    const float* z = (const float*)d_in[0];
    const float* c = (const float*)d_in[1];
    const float* W = (const float*)d_in[2];
    const float* b = (const float*)d_in[3];
    const int* batch_index = (const int*)d_in[4];
    const int* seq_index   = (const int*)d_in[5];
    float* out = (float*)d_out;

    hipMemsetAsync(out, 0, 7 * sizeof(float), stream);
    dim3 grid(K_N * S_N * U_N * 8);  // 3072
    cpc_fused<<<grid, dim3(256), 0, stream>>>(z, c, W, b, batch_index, seq_index, out);
}